// Round 8
// baseline (16320.969 us; speedup 1.0000x reference)
//
#include <hip/hip_runtime.h>
#include <math.h>

#define LSEQ 512
#define BATCH 64
#define HID 1024
#define NCH 8
#define GSZ 4112
#define NBLK 64

typedef __bf16 bf16x8 __attribute__((ext_vector_type(8)));
typedef float f32x4 __attribute__((ext_vector_type(4)));
typedef unsigned u32x4 __attribute__((ext_vector_type(4)));

__device__ __forceinline__ ushort f2b(float f) {
  union { float f; unsigned u; } v; v.f = f;
  unsigned u = v.u;
  unsigned r = (u + 0x7FFFu + ((u >> 16) & 1u)) >> 16;  // RNE
  return (ushort)r;
}
__device__ __forceinline__ float b2f(ushort h) {
  union { unsigned u; float f; } v; v.u = (unsigned)h << 16; return v.f;
}
__device__ __forceinline__ float sigmoidf(float x) { return 1.f / (1.f + expf(-x)); }

// ---- transpose + cast: W (K x N) f32 -> WT (N x K) bf16 ----
__global__ __launch_bounds__(256) void k_transpose_cast(
    const float* __restrict__ W, ushort* __restrict__ WT, int K, int N) {
  __shared__ float tile[32][33];
  int n0 = blockIdx.x * 32, k0 = blockIdx.y * 32;
  int tx = threadIdx.x & 31, ty = threadIdx.x >> 5;
  #pragma unroll
  for (int i = ty; i < 32; i += 8) {
    int n = n0 + tx;
    tile[i][tx] = (n < N) ? W[(size_t)(k0 + i) * N + n] : 0.f;
  }
  __syncthreads();
  #pragma unroll
  for (int i = ty; i < 32; i += 8) {
    int n = n0 + i;
    if (n < N) WT[(size_t)n * K + k0 + tx] = f2b(tile[tx][i]);
  }
}

// ---- f32 -> bf16 cast (vectorized x4) ----
__global__ void k_cast4(const float4* __restrict__ in, ushort* __restrict__ out, int count4) {
  int stride = gridDim.x * blockDim.x;
  for (int i = blockIdx.x * blockDim.x + threadIdx.x; i < count4; i += stride) {
    float4 v = in[i];
    ushort4 o;
    o.x = f2b(v.x); o.y = f2b(v.y); o.z = f2b(v.z); o.w = f2b(v.w);
    *reinterpret_cast<ushort4*>(out + (size_t)i * 4) = o;
  }
}

__global__ void k_init_state(const float* __restrict__ h0l, const float* __restrict__ c0l,
                             ushort* __restrict__ hb, float* __restrict__ c,
                             unsigned* __restrict__ barmem, int count) {
  int i = blockIdx.x * blockDim.x + threadIdx.x;
  if (i < count) { hb[i] = f2b(h0l[i]); c[i] = c0l[i]; }
  if (i < NBLK * 16) barmem[i] = 0u;  // per-block flag cachelines
}

// Ct[t][col][batch] (bf16) = A[t*64+b][K](bf16) @ BT[col][K](bf16)^T + bias[col]
__global__ __launch_bounds__(256) void k_gemm_t(
    const ushort* __restrict__ A, const ushort* __restrict__ BT,
    const float* __restrict__ bias, ushort* __restrict__ Ct, int K, int N) {
  int col0 = blockIdx.x * 64;
  int t = blockIdx.y;
  int lane = threadIdx.x & 63;
  int w = threadIdx.x >> 6;
  int l15 = lane & 15;
  int koff = (lane >> 4) * 8;
  const ushort* Ap = A + (size_t)(t * 64 + w * 16 + l15) * K + koff;
  const ushort* Bp[4];
  int cols[4];
  #pragma unroll
  for (int cg = 0; cg < 4; ++cg) {
    int c_ = col0 + cg * 16 + l15;
    cols[cg] = c_;
    int cc = c_ < N ? c_ : N - 1;  // clamp reads on partial tile
    Bp[cg] = BT + (size_t)cc * K + koff;
  }
  f32x4 acc[4] = {};
  #pragma unroll 4
  for (int kk = 0; kk < K; kk += 32) {
    bf16x8 a = *reinterpret_cast<const bf16x8*>(Ap + kk);
    #pragma unroll
    for (int cg = 0; cg < 4; ++cg) {
      bf16x8 b = *reinterpret_cast<const bf16x8*>(Bp[cg] + kk);
      acc[cg] = __builtin_amdgcn_mfma_f32_16x16x32_bf16(a, b, acc[cg], 0, 0, 0);
    }
  }
  int crow = w * 16 + (lane >> 4) * 4;  // batch row base
  #pragma unroll
  for (int cg = 0; cg < 4; ++cg) {
    int c_ = cols[cg];
    if (c_ >= N) continue;
    float bv = bias[c_];
    ushort4 o;
    o.x = f2b(acc[cg][0] + bv); o.y = f2b(acc[cg][1] + bv);
    o.z = f2b(acc[cg][2] + bv); o.w = f2b(acc[cg][3] + bv);
    *reinterpret_cast<ushort4*>(&Ct[((size_t)t * GSZ + c_) * 64 + crow]) = o;
  }
}

// ---- persistent scan: 64 blocks x 1024 threads (16 waves) ----
// GEMM phase: 5 waves, wave g owns ONE 16-col tile (g=0: softmax cols,
// g=1..4: out/cell/in/fg for the block's 16 hidden units) and iterates all
// 4 batch tiles, reusing each B-frag from registers (min L1 traffic).
// Barrier: per-block flag cachelines (stores) + 64-lane gather poll. No
// atomics, no L2 flush. out stores deferred past the barrier.
__global__ __launch_bounds__(1024, 4) void k_scan(
    const ushort* __restrict__ WhhT,  // [GSZ][HID] bf16
    const float* __restrict__ bhh,
    const ushort* __restrict__ tin,   // [nsteps][GSZ][64] bf16
    ushort* __restrict__ hbuf0, ushort* __restrict__ hbuf1,  // [64][1024] bf16
    float* __restrict__ cws,          // [64][1024] f32
    float* __restrict__ out_hs, float* __restrict__ out_hs2,
    float* __restrict__ dfs, float* __restrict__ dins,
    float* __restrict__ hT, float* __restrict__ cT,
    unsigned* __restrict__ barmem, int nsteps, int barbase) {
  __shared__ unsigned hlds[32768];            // 128 KB: h staged, XOR-swizzled
  __shared__ __align__(16) float gbuf[80][68];  // [col][batch]

  const int tid = threadIdx.x;
  const int blk = blockIdx.x;
  const int j0 = blk * 16;
  const int lane = tid & 63;
  const int w = tid >> 6;       // wave 0..15
  const int l15 = lane & 15;
  const int koff = (lane >> 4) * 8;

  // GEMM-wave constants (w < 5)
  const int gcol = (w == 0) ? l15 : (16 + (w - 1) * 1024 + j0 + l15);
  const ushort* bp = WhhT + (size_t)gcol * HID + koff;
  const float bv = bhh[gcol];
  const int grow = (w == 0) ? l15 : (16 + (w - 1) * 16 + l15);
  const int cr = (lane >> 4) << 2;  // batch sub-row within 16-row tile
  const unsigned ab = (unsigned)l15 * 2048u + (unsigned)koff * 2u;
  const unsigned swz = (unsigned)(l15 & 7) << 4;

  // cell mapping: thread -> (batch cb, local hidden jl)
  const int cb = tid >> 4;
  const int jl = tid & 15;
  const int jglob = j0 + jl;
  const int r = jglob >> 7;
  float creg = cws[cb * HID + jglob];

  float def_hy = 0.f, def_df = 0.f, def_di = 0.f;
  size_t def_oidx = 0;

  for (int tt = 0; tt < nsteps; ++tt) {
    // ---- (A) deferred output stores from step tt-1 (off critical path) ----
    if (tt > 0) {
      out_hs[def_oidx] = def_hy;
      if (out_hs2) out_hs2[def_oidx] = def_hy;
      if (blk == 0 && jl == 0) {
        dfs[(tt - 1) * BATCH + cb] = def_df;
        dins[(tt - 1) * BATCH + cb] = def_di;
      }
    }

    // ---- (B/C) stage h (coherent LLC read) -> LDS, swizzled ----
    const u32x4* hs = (const u32x4*)((tt & 1) ? hbuf1 : hbuf0);
    u32x4 v0, v1, v2, v3, v4, v5, v6, v7;
#define CLOAD(dst, I) asm volatile("global_load_dwordx4 %0, %1, off sc0 sc1" \
      : "=v"(dst) : "v"(hs + tid + (I)*1024) : "memory")
    CLOAD(v0, 0); CLOAD(v1, 1); CLOAD(v2, 2); CLOAD(v3, 3);
    CLOAD(v4, 4); CLOAD(v5, 5); CLOAD(v6, 6); CLOAD(v7, 7);
#undef CLOAD
    asm volatile("s_waitcnt vmcnt(0)" ::: "memory");
    __builtin_amdgcn_sched_barrier(0);
#define WST(v, I) { unsigned byte_ = (unsigned)(tid + (I)*1024) * 16u; \
    unsigned row_ = byte_ >> 11; \
    *(u32x4*)((char*)hlds + (byte_ ^ ((row_ & 7u) << 4))) = v; }
    WST(v0, 0); WST(v1, 1); WST(v2, 2); WST(v3, 3);
    WST(v4, 4); WST(v5, 5); WST(v6, 6); WST(v7, 7);
#undef WST
    __syncthreads();

    // ---- (D) GEMM: 5 waves, one col-tile each, 4 batch tiles ----
    if (w < 5) {
      const ushort* tp = tin + ((size_t)tt * GSZ + gcol) * 64 + cr;
      ushort4 tv0 = *(const ushort4*)(tp);
      ushort4 tv1 = *(const ushort4*)(tp + 16);
      ushort4 tv2 = *(const ushort4*)(tp + 32);
      ushort4 tv3 = *(const ushort4*)(tp + 48);
      f32x4 a0 = {}, a1 = {}, a2 = {}, a3 = {};
      #pragma unroll 4
      for (int kb = 0; kb < 32; ++kb) {
        bf16x8 b = *(const bf16x8*)(bp + kb * 32);
        unsigned o = ab + (unsigned)kb * 64u;
        bf16x8 x0 = *(const bf16x8*)((const char*)hlds + ((o)           ^ swz));
        bf16x8 x1 = *(const bf16x8*)((const char*)hlds + ((o + 32768u)  ^ swz));
        bf16x8 x2 = *(const bf16x8*)((const char*)hlds + ((o + 65536u)  ^ swz));
        bf16x8 x3 = *(const bf16x8*)((const char*)hlds + ((o + 98304u)  ^ swz));
        a0 = __builtin_amdgcn_mfma_f32_16x16x32_bf16(x0, b, a0, 0, 0, 0);
        a1 = __builtin_amdgcn_mfma_f32_16x16x32_bf16(x1, b, a1, 0, 0, 0);
        a2 = __builtin_amdgcn_mfma_f32_16x16x32_bf16(x2, b, a2, 0, 0, 0);
        a3 = __builtin_amdgcn_mfma_f32_16x16x32_bf16(x3, b, a3, 0, 0, 0);
      }
      f32x4 g;
      g[0] = a0[0] + bv + b2f(tv0.x); g[1] = a0[1] + bv + b2f(tv0.y);
      g[2] = a0[2] + bv + b2f(tv0.z); g[3] = a0[3] + bv + b2f(tv0.w);
      *(f32x4*)(&gbuf[grow][cr]) = g;
      g[0] = a1[0] + bv + b2f(tv1.x); g[1] = a1[1] + bv + b2f(tv1.y);
      g[2] = a1[2] + bv + b2f(tv1.z); g[3] = a1[3] + bv + b2f(tv1.w);
      *(f32x4*)(&gbuf[grow][16 + cr]) = g;
      g[0] = a2[0] + bv + b2f(tv2.x); g[1] = a2[1] + bv + b2f(tv2.y);
      g[2] = a2[2] + bv + b2f(tv2.z); g[3] = a2[3] + bv + b2f(tv2.w);
      *(f32x4*)(&gbuf[grow][32 + cr]) = g;
      g[0] = a3[0] + bv + b2f(tv3.x); g[1] = a3[1] + bv + b2f(tv3.y);
      g[2] = a3[2] + bv + b2f(tv3.z); g[3] = a3[3] + bv + b2f(tv3.w);
      *(f32x4*)(&gbuf[grow][48 + cr]) = g;
    }
    __syncthreads();

    // ---- (E) fused cell update (all 1024 threads) ----
    float sm0[NCH], sm1[NCH];
    float m1 = -1e30f, m2 = -1e30f;
    #pragma unroll
    for (int i = 0; i < NCH; ++i) {
      sm0[i] = gbuf[i][cb];
      sm1[i] = gbuf[NCH + i][cb];
      m1 = fmaxf(m1, sm0[i]);
      m2 = fmaxf(m2, sm1[i]);
    }
    float s1 = 0.f, s2 = 0.f;
    #pragma unroll
    for (int i = 0; i < NCH; ++i) {
      sm0[i] = expf(sm0[i] - m1); s1 += sm0[i];
      sm1[i] = expf(sm1[i] - m2); s2 += sm1[i];
    }
    float r1 = 1.f / s1, r2 = 1.f / s2;
    float cum1 = 0.f, cum2 = 0.f, sumin = 0.f, sumfg = 0.f;
    float cing[NCH], cfg[NCH];
    #pragma unroll
    for (int i = 0; i < NCH; ++i) {
      cum1 += sm0[i] * r1; cing[i] = 1.f - cum1; sumin += cing[i];
      cum2 += sm1[i] * r2; cfg[i] = cum2; sumfg += cfg[i];
    }
    float go = gbuf[16 + jl][cb];
    float gc = gbuf[32 + jl][cb];
    float gi = gbuf[48 + jl][cb];
    float gf = gbuf[64 + jl][cb];
    float ov = cfg[r] * cing[r];
    float f_ = sigmoidf(gf) * ov + (cfg[r] - ov);
    float i_ = sigmoidf(gi) * ov + (cing[r] - ov);
    float cy = f_ * creg + i_ * tanhf(gc);
    float hy = sigmoidf(go) * tanhf(cy);
    creg = cy;

    // ---- (F) h store: write-through to LLC, packed bf16 pairs ----
    ushort hv = f2b(hy);
    unsigned other = (unsigned)__shfl_xor((int)(unsigned)hv, 1, 64);
    ushort* hw = ((tt & 1) ? hbuf0 : hbuf1) + cb * HID + j0 + jl;
    if ((jl & 1) == 0) {
      unsigned pk = (unsigned)hv | (other << 16);
      asm volatile("global_store_dword %0, %1, off sc0 sc1" :: "v"(hw), "v"(pk) : "memory");
    }
    if (hT && tt == nsteps - 1) {
      hT[cb * HID + jglob] = hy;
      cT[cb * HID + jglob] = cy;
    }

    // ---- (G) defer output stores to next iteration ----
    def_hy = hy;
    def_oidx = ((size_t)tt * BATCH + cb) * HID + jglob;
    def_df = 1.f - sumfg * 0.125f;
    def_di = sumin * 0.125f;

    // ---- (H) flag barrier: own-line store + 64-lane gather poll ----
    if (tt < nsteps - 1) {
      asm volatile("s_waitcnt vmcnt(0)" ::: "memory");  // h store at LLC
      __syncthreads();
      if (w == 0) {
        unsigned tgt = (unsigned)(barbase + tt + 1);
        if (lane == 0) {
          unsigned* fp = barmem + (unsigned)blk * 16u;
          asm volatile("global_store_dword %0, %1, off sc0 sc1"
                       :: "v"(fp), "v"(tgt) : "memory");
        }
        const unsigned* mp = barmem + (unsigned)lane * 16u;
        while (true) {
          unsigned f;
          asm volatile("global_load_dword %0, %1, off sc0 sc1"
                       : "=v"(f) : "v"(mp) : "memory");
          asm volatile("s_waitcnt vmcnt(0)" ::: "memory");
          if (__all((int)(f >= tgt))) break;
        }
      }
      __syncthreads();
    }
  }
  // flush deferred stores of the last step
  out_hs[def_oidx] = def_hy;
  if (out_hs2) out_hs2[def_oidx] = def_hy;
  if (blk == 0 && jl == 0) {
    dfs[(nsteps - 1) * BATCH + cb] = def_df;
    dins[(nsteps - 1) * BATCH + cb] = def_di;
  }
  cws[cb * HID + jglob] = creg;
}

extern "C" void kernel_launch(void* const* d_in, const int* in_sizes, int n_in,
                              void* d_out, int out_size, void* d_ws, size_t ws_size,
                              hipStream_t stream) {
  const float* x   = (const float*)d_in[0];
  const float* h0  = (const float*)d_in[1];
  const float* c0  = (const float*)d_in[2];
  const float* Wih = (const float*)d_in[3];
  const float* bih = (const float*)d_in[4];
  const float* Whh = (const float*)d_in[5];
  const float* bhh = (const float*)d_in[6];
  float* out = (float*)d_out;

  const size_t OFF_OUTPUT = 0;                  // (512,64,1024)
  const size_t OFF_HT   = 33554432;             // (2,64,1024)
  const size_t OFF_CT   = OFF_HT + 131072;      // (2,64,8,128)
  const size_t OFF_OUTS = OFF_CT + 131072;      // (2,512,64,1024)
  const size_t OFF_DFS  = OFF_OUTS + 67108864;  // (2,512,64)
  const size_t OFF_DINS = OFF_DFS + 65536;      // (2,512,64)

  uint8_t* ws = (uint8_t*)d_ws;
  size_t off = 0;
  auto alloc = [&](size_t bytes) { size_t p = off; off = (off + bytes + 255) & ~(size_t)255; return p; };
  const size_t wT_sz = (size_t)GSZ * HID * 2;
  size_t o_WihT[2], o_WhhT[2];
  o_WihT[0] = alloc(wT_sz); o_WihT[1] = alloc(wT_sz);
  o_WhhT[0] = alloc(wT_sz); o_WhhT[1] = alloc(wT_sz);
  size_t o_h0b = alloc((size_t)BATCH * HID * 2);
  size_t o_h1b = alloc((size_t)BATCH * HID * 2);
  size_t o_c   = alloc((size_t)BATCH * HID * 4);
  size_t o_bar = alloc(4096);
  size_t fixed = off;
  const size_t unit = (size_t)BATCH * HID * 2 + (size_t)BATCH * GSZ * 2 + 512;
  int TC = 256;
  while (TC > 2 && fixed + (size_t)TC * unit > ws_size) TC >>= 1;
  size_t o_prevb = alloc((size_t)TC * BATCH * HID * 2);
  size_t o_tin   = alloc((size_t)TC * BATCH * GSZ * 2);

  ushort* hb0 = (ushort*)(ws + o_h0b);
  ushort* hb1 = (ushort*)(ws + o_h1b);
  float*  cst = (float*)(ws + o_c);
  unsigned* barmem = (unsigned*)(ws + o_bar);
  ushort* prevb = (ushort*)(ws + o_prevb);
  ushort* tin   = (ushort*)(ws + o_tin);

  dim3 tgrid((GSZ + 31) / 32, HID / 32);
  for (int l = 0; l < 2; ++l) {
    k_transpose_cast<<<tgrid, 256, 0, stream>>>(Wih + (size_t)l * HID * GSZ,
                                                (ushort*)(ws + o_WihT[l]), HID, GSZ);
    k_transpose_cast<<<tgrid, 256, 0, stream>>>(Whh + (size_t)l * HID * GSZ,
                                                (ushort*)(ws + o_WhhT[l]), HID, GSZ);
  }

  const int NB = (GSZ + 63) / 64;
  for (int l = 0; l < 2; ++l) {
    const float* prev = (l == 0) ? x : (out + OFF_OUTS);  // layer-0 hs in outs[0]
    const ushort* WihT = (const ushort*)(ws + o_WihT[l]);

    k_init_state<<<256, 256, 0, stream>>>(h0 + (size_t)l * BATCH * HID,
                                          c0 + (size_t)l * BATCH * HID,
                                          hb0, cst, barmem, BATCH * HID);

    int barbase = 0;  // cumulative barrier rounds this layer
    for (int t0 = 0; t0 < LSEQ; t0 += TC) {
      int nsteps = (LSEQ - t0 < TC) ? (LSEQ - t0) : TC;

      int count4 = nsteps * BATCH * HID / 4;
      int cblocks = (count4 + 255) / 256; if (cblocks > 2048) cblocks = 2048;
      k_cast4<<<cblocks, 256, 0, stream>>>(
          (const float4*)(prev + (size_t)t0 * BATCH * HID), prevb, count4);

      k_gemm_t<<<dim3(NB, nsteps), 256, 0, stream>>>(prevb, WihT,
                                                     bih + (size_t)l * GSZ, tin, HID, GSZ);

      bool last = (t0 + nsteps == LSEQ);
      const ushort* WhhT_p = (const ushort*)(ws + o_WhhT[l]);
      const float* bhh_p = bhh + (size_t)l * GSZ;
      const ushort* tin_p = tin;
      ushort* h0_p = hb0;
      ushort* h1_p = hb1;
      float* c_p = cst;
      float* ohs  = out + OFF_OUTS + ((size_t)l * LSEQ + t0) * BATCH * HID;
      float* ohs2 = (l == 1) ? (out + OFF_OUTPUT + (size_t)t0 * BATCH * HID) : nullptr;
      float* dfsp  = out + OFF_DFS  + ((size_t)l * LSEQ + t0) * BATCH;
      float* dinsp = out + OFF_DINS + ((size_t)l * LSEQ + t0) * BATCH;
      float* hTp = last ? (out + OFF_HT + (size_t)l * BATCH * HID) : nullptr;
      float* cTp = last ? (out + OFF_CT + (size_t)l * BATCH * HID) : nullptr;
      int nsteps_v = nsteps;
      int barbase_v = barbase;

      void* args[] = {&WhhT_p, &bhh_p, &tin_p, &h0_p, &h1_p, &c_p, &ohs, &ohs2,
                      &dfsp, &dinsp, &hTp, &cTp, &barmem, &nsteps_v, &barbase_v};
      hipLaunchCooperativeKernel((const void*)k_scan, dim3(NBLK), dim3(1024),
                                 args, 0, stream);
      barbase += nsteps - 1;

      // h parity: if nsteps is odd the final h landed in the "other" buffer
      if (nsteps & 1) { ushort* tmp = hb0; hb0 = hb1; hb1 = tmp; }
    }
  }
}